// Round 17
// baseline (302.552 us; speedup 1.0000x reference)
//
#include <hip/hip_runtime.h>
#include <hip/hip_bf16.h>
#include <math.h>

#define NN 4096
#define NE 131072
#define DIM 256
#define NHEAD 8
#define HD 32

typedef __attribute__((ext_vector_type(8))) short short8v;
typedef __attribute__((ext_vector_type(4))) float f32x4;
#define MFMA16(a, b, c) __builtin_amdgcn_mfma_f32_16x16x32_bf16(a, b, c, 0, 0, 0)

__device__ __forceinline__ float elu_f(float v){ return v > 0.f ? v : expm1f(v); }
__device__ __forceinline__ float gelu_f(float v){
  const float c = 0.7978845608028654f;
  float t = tanhf(c * (v + 0.044715f * v * v * v));
  return 0.5f * v * (1.f + t);
}
__device__ __forceinline__ unsigned short f2bf(float f) {
  unsigned int u = __builtin_bit_cast(unsigned int, f);
  u += 0x7FFFu + ((u >> 16) & 1u);
  return (unsigned short)(u >> 16);
}
__device__ __forceinline__ float bf2f(unsigned short u) {
  return __builtin_bit_cast(float, (unsigned int)u << 16);
}
__device__ __forceinline__ unsigned int pk2c(float a, float b) {
  __hip_bfloat162 h = __float22bfloat162_rn(float2{a, b});
  unsigned int r;
  __builtin_memcpy(&r, &h, 4);
  return r;
}

// ---------------- CSR build ----------------
__global__ void count_edges(const int* __restrict__ ei, int* __restrict__ counts) {
  int e = blockIdx.x * 256 + threadIdx.x;
  if (e < NE) atomicAdd(&counts[ei[NE + e]], 1);
}

__global__ __launch_bounds__(1024) void scan_offsets(const int* __restrict__ counts,
                                                     int* __restrict__ offs,
                                                     int* __restrict__ cursor) {
  __shared__ int tmp[1024];
  int t = threadIdx.x;
  int base = t * 4;
  int c0 = counts[base], c1 = counts[base+1], c2 = counts[base+2], c3 = counts[base+3];
  int tsum = c0 + c1 + c2 + c3;
  tmp[t] = tsum;
  __syncthreads();
  for (int d = 1; d < 1024; d <<= 1) {
    int v = (t >= d) ? tmp[t - d] : 0;
    __syncthreads();
    tmp[t] += v;
    __syncthreads();
  }
  int excl = tmp[t] - tsum;
  offs[base]   = excl;           cursor[base]   = excl;
  offs[base+1] = excl + c0;      cursor[base+1] = excl + c0;
  offs[base+2] = excl + c0 + c1; cursor[base+2] = excl + c0 + c1;
  offs[base+3] = excl + c0 + c1 + c2; cursor[base+3] = excl + c0 + c1 + c2;
  if (t == 1023) offs[NN] = tmp[1023];
}

__global__ void scatter_edges(const int* __restrict__ ei, int* __restrict__ cursor,
                              int* __restrict__ esrc) {
  int e = blockIdx.x * 256 + threadIdx.x;
  if (e < NE) {
    int d = ei[NE + e];
    int pos = atomicAdd(&cursor[d], 1);
    esrc[pos] = ei[e];
  }
}

// ---------------- GIN aggregate v2: wave per node, ushort4 (8B/lane) gather ----------------
__global__ __launch_bounds__(256) void gin_agg(const int* __restrict__ offs,
                                               const int* __restrict__ esrc,
                                               const unsigned short* __restrict__ xb,
                                               const float* __restrict__ eps_p, int l,
                                               unsigned short* __restrict__ aggb) {
  int w = threadIdx.x >> 6, lane = threadIdx.x & 63;
  int n = blockIdx.x * 4 + w;
  int c = lane * 4;
  int e0 = offs[n], e1 = offs[n + 1];
  float a0 = 0.f, a1 = 0.f, a2 = 0.f, a3 = 0.f;
  for (int e = e0; e < e1; e++) {
    ushort4 v = *(const ushort4*)(xb + (size_t)esrc[e] * DIM + c);
    a0 += bf2f(v.x); a1 += bf2f(v.y); a2 += bf2f(v.z); a3 += bf2f(v.w);
  }
  float eps = 1.f + eps_p[l];
  ushort4 xv = *(const ushort4*)(xb + (size_t)n * DIM + c);
  ushort4 o;
  o.x = f2bf(eps * bf2f(xv.x) + a0);
  o.y = f2bf(eps * bf2f(xv.y) + a1);
  o.z = f2bf(eps * bf2f(xv.z) + a2);
  o.w = f2bf(eps * bf2f(xv.w) + a3);
  *(ushort4*)(aggb + (size_t)n * DIM + c) = o;
}

// ---------------- bf16 MFMA GEMM v4: 64x32 tile, reg dbuf, optional grid split-K ----------
// SPLITK>1: blockIdx.z owns K-range [z*K/SPLITK, ...); partials to Cf + z*M*N (bias on z=0).
template<int ACT, int WF32, int WBF16, int QSCALE, int BK, int WVT = 0, int SPLITK = 1>
__global__ __launch_bounds__(256) void gemm_mfma(
    const unsigned short* __restrict__ A, const unsigned short* __restrict__ W,
    const float* __restrict__ bias, float* __restrict__ Cf,
    unsigned short* __restrict__ Cb, int M, int N, int K,
    unsigned short* __restrict__ VTout = nullptr)
{
  __shared__ __align__(16) unsigned short As[2][64][BK + 8];
  __shared__ __align__(16) unsigned short Ws[2][32][BK + 8];
  constexpr int CPR = BK / 8;
  constexpr int ACH = 64 * CPR;
  constexpr int WCH = 32 * CPR;
  constexpr int NA = (ACH + 255) / 256;
  constexpr int NW = (WCH + 255) / 256;
  int t = threadIdx.x;
  int w = t >> 6, lane = t & 63, lo = lane & 15, g = lane >> 4;
  int wm = w & 1, wn = w >> 1;
  int bn = blockIdx.x * 32, bm = blockIdx.y * 64;
  int kz0 = 0, kz1 = K;
  if (SPLITK > 1) {
    int kspan = K / SPLITK;
    kz0 = blockIdx.z * kspan;
    kz1 = kz0 + kspan;
  }

  f32x4 acc0 = {0.f, 0.f, 0.f, 0.f};
  f32x4 acc1 = {0.f, 0.f, 0.f, 0.f};
  short8v pa[NA], pw[NW];

  auto LOADG = [&](int k0) {
    #pragma unroll
    for (int i = 0; i < NA; i++) {
      int cc = i * 256 + t;
      int row = cc / CPR, off = (cc % CPR) * 8;
      pa[i] = *(const short8v*)(A + (size_t)(bm + row) * K + k0 + off);
    }
    #pragma unroll
    for (int i = 0; i < NW; i++) {
      int cc = i * 256 + t;
      if (cc < WCH) {
        int row = cc / CPR, off = (cc % CPR) * 8;
        pw[i] = *(const short8v*)(W + (size_t)(bn + row) * K + k0 + off);
      }
    }
  };
  auto STORE = [&](int b) {
    #pragma unroll
    for (int i = 0; i < NA; i++) {
      int cc = i * 256 + t;
      int row = cc / CPR, off = (cc % CPR) * 8;
      *(short8v*)&As[b][row][off] = pa[i];
    }
    #pragma unroll
    for (int i = 0; i < NW; i++) {
      int cc = i * 256 + t;
      if (cc < WCH) {
        int row = cc / CPR, off = (cc % CPR) * 8;
        *(short8v*)&Ws[b][row][off] = pw[i];
      }
    }
  };

  LOADG(kz0);
  STORE(0);
  __syncthreads();

  int buf = 0;
  for (int k0 = kz0; k0 < kz1; k0 += BK) {
    bool more = (k0 + BK < kz1);
    if (more) LOADG(k0 + BK);
    #pragma unroll
    for (int ks = 0; ks < BK; ks += 32) {
      short8v a0 = *(const short8v*)&As[buf][wm * 32 + lo][ks + 8 * g];
      short8v a1 = *(const short8v*)&As[buf][wm * 32 + 16 + lo][ks + 8 * g];
      short8v b0 = *(const short8v*)&Ws[buf][wn * 16 + lo][ks + 8 * g];
      acc0 = MFMA16(a0, b0, acc0);
      acc1 = MFMA16(a1, b0, acc1);
    }
    if (more) STORE(buf ^ 1);
    __syncthreads();
    buf ^= 1;
  }

  float* Cfz = Cf;
  if (SPLITK > 1 && Cf) Cfz = Cf + (size_t)blockIdx.z * M * N;

  #pragma unroll
  for (int mi = 0; mi < 2; mi++) {
    f32x4 av = (mi == 0) ? acc0 : acc1;
    int col = bn + wn * 16 + lo;
    int rbase = bm + wm * 32 + mi * 16 + 4 * g;
    float bv = (SPLITK == 1 || blockIdx.z == 0) ? bias[col] : 0.f;
    if (WVT && col >= 512) {
      ushort4 o;
      float v0 = av[0] + bv, v1 = av[1] + bv;
      float v2 = av[2] + bv, v3 = av[3] + bv;
      o.x = f2bf(v0); o.y = f2bf(v1); o.z = f2bf(v2); o.w = f2bf(v3);
      *(ushort4*)(VTout + (size_t)(col - 512) * 4096 + rbase) = o;
    } else {
      #pragma unroll
      for (int r = 0; r < 4; r++) {
        int row = rbase + r;
        float v = av[r] + bv;
        if (ACT == 1) v = elu_f(v);
        if (ACT == 2) v = gelu_f(v);
        if (QSCALE) { if (col < 256) v *= 0.17677669529663687f; }
        if (WF32) Cfz[(size_t)row * N + col] = v;
        if (WBF16) Cb[(size_t)row * N + col] = f2bf(v);
      }
    }
  }
}

// ---------------- LayerNorm v3: wave per row, float4 I/O; NS=2 sums split-K partials ------
template<int ACT, int NS>
__global__ __launch_bounds__(256) void ln_act_add(const float* __restrict__ in,
                                                  const float* __restrict__ g,
                                                  const float* __restrict__ b,
                                                  float* __restrict__ x,
                                                  unsigned short* __restrict__ xb) {
  int w = threadIdx.x >> 6, lane = threadIdx.x & 63;
  int row = blockIdx.x * 4 + w;
  int c = lane * 4;
  float4 v = *(const float4*)(in + (size_t)row * DIM + c);
  if (NS == 2) {
    float4 v1 = *(const float4*)(in + (size_t)NN * DIM + (size_t)row * DIM + c);
    v.x += v1.x; v.y += v1.y; v.z += v1.z; v.w += v1.w;
  }
  float s  = (v.x + v.y) + (v.z + v.w);
  float s2 = (v.x * v.x + v.y * v.y) + (v.z * v.z + v.w * v.w);
  #pragma unroll
  for (int off = 32; off >= 1; off >>= 1) {
    s  += __shfl_xor(s,  off, 64);
    s2 += __shfl_xor(s2, off, 64);
  }
  float mean = s * (1.f / DIM);
  float var = s2 * (1.f / DIM) - mean * mean;
  float r = rsqrtf(var + 1e-5f);
  float4 gg = *(const float4*)(g + c);
  float4 bb = *(const float4*)(b + c);
  float4 o;
  o.x = (v.x - mean) * r * gg.x + bb.x;
  o.y = (v.y - mean) * r * gg.y + bb.y;
  o.z = (v.z - mean) * r * gg.z + bb.z;
  o.w = (v.w - mean) * r * gg.w + bb.w;
  if (ACT == 1) { o.x = elu_f(o.x); o.y = elu_f(o.y); o.z = elu_f(o.z); o.w = elu_f(o.w); }
  float4 xv = *(const float4*)(x + (size_t)row * DIM + c);
  xv.x += o.x; xv.y += o.y; xv.z += o.z; xv.w += o.w;
  *(float4*)(x + (size_t)row * DIM + c) = xv;
  ushort4 xo;
  xo.x = f2bf(xv.x); xo.y = f2bf(xv.y); xo.z = f2bf(xv.z); xo.w = f2bf(xv.w);
  *(ushort4*)(xb + (size_t)row * DIM + c) = xo;
}

// ---------------- MFMA flash attention v7 (R14-proven): 8-wave QB=128, LDS K/V, in-reg SM --
__global__ __launch_bounds__(512) void attn_mfma_split(
    const unsigned short* __restrict__ qkvb, const unsigned short* __restrict__ VT,
    float* __restrict__ po, float* __restrict__ ml, int kspan) {
  __shared__ __align__(16) unsigned short Ks[2][64][40];
  __shared__ __align__(16) unsigned short Vs[2][32][72];
  int tid = threadIdx.x;
  int w = tid >> 6, lane = tid & 63;
  int lo = lane & 15, g = lane >> 4;
  int h = blockIdx.y;
  int s = blockIdx.z;
  int qb = blockIdx.x * 128 + w * 16;
  int k_lo = s * kspan, k_hi = k_lo + kspan;

  bool isK = tid < 256;
  int krow = tid >> 2, kq = (tid & 3) * 8;
  int vtid = tid & 255;
  int vrow = vtid >> 3, vo = (vtid & 7) * 8;
  const unsigned short* Kg = qkvb + 256 + h * 32;
  const unsigned short* Vg = VT + ((size_t)(h * 32 + vrow)) * 4096;

  short8v qf = *(const short8v*)(qkvb + (size_t)(qb + lo) * 768 + h * 32 + 8 * g);

  f32x4 acc0 = {0.f, 0.f, 0.f, 0.f};
  f32x4 acc1 = {0.f, 0.f, 0.f, 0.f};
  float m = -1e30f, l = 0.f;
  const f32x4 zf = {0.f, 0.f, 0.f, 0.f};

  {
    if (isK) {
      short8v rk0 = *(const short8v*)(Kg + (size_t)(k_lo + krow) * 768 + kq);
      *(short8v*)&Ks[0][krow][kq] = rk0;
    } else {
      short8v rv0 = *(const short8v*)(Vg + k_lo + vo);
      *(short8v*)&Vs[0][vrow][vo] = rv0;
    }
  }
  __syncthreads();

  int buf = 0;
  for (int kb = k_lo; kb < k_hi; kb += 64) {
    short8v rg;
    bool more = (kb + 64 < k_hi);
    if (more) {
      if (isK) rg = *(const short8v*)(Kg + (size_t)(kb + 64 + krow) * 768 + kq);
      else     rg = *(const short8v*)(Vg + kb + 64 + vo);
    }

    short8v kA0 = *(const short8v*)&Ks[buf][lo][8 * g];
    short8v kA1 = *(const short8v*)&Ks[buf][16 + lo][8 * g];
    short8v kA2 = *(const short8v*)&Ks[buf][32 + lo][8 * g];
    short8v kA3 = *(const short8v*)&Ks[buf][48 + lo][8 * g];
    f32x4 s0_ = MFMA16(kA0, qf, zf);
    f32x4 s1_ = MFMA16(kA1, qf, zf);
    f32x4 s2_ = MFMA16(kA2, qf, zf);
    f32x4 s3_ = MFMA16(kA3, qf, zf);

    float ta_ = fmaxf(fmaxf(fmaxf(s0_[0],s0_[1]), fmaxf(s0_[2],s0_[3])),
                      fmaxf(fmaxf(s1_[0],s1_[1]), fmaxf(s1_[2],s1_[3])));
    float tb_ = fmaxf(fmaxf(fmaxf(s2_[0],s2_[1]), fmaxf(s2_[2],s2_[3])),
                      fmaxf(fmaxf(s3_[0],s3_[1]), fmaxf(s3_[2],s3_[3])));
    float t_ = fmaxf(ta_, tb_);
    t_ = fmaxf(t_, __shfl_xor(t_, 16, 64));
    t_ = fmaxf(t_, __shfl_xor(t_, 32, 64));
    if (!__all(t_ <= m)) {
      float nm_ = fmaxf(m, t_);
      float f_ = __expf(m - nm_);
      m = nm_; l *= f_;
      acc0[0]*=f_; acc0[1]*=f_; acc0[2]*=f_; acc0[3]*=f_;
      acc1[0]*=f_; acc1[1]*=f_; acc1[2]*=f_; acc1[3]*=f_;
    }
    float p0_=__expf(s0_[0]-m), p1_=__expf(s0_[1]-m), p2_=__expf(s0_[2]-m), p3_=__expf(s0_[3]-m);
    float p4_=__expf(s1_[0]-m), p5_=__expf(s1_[1]-m), p6_=__expf(s1_[2]-m), p7_=__expf(s1_[3]-m);
    float p8_=__expf(s2_[0]-m), p9_=__expf(s2_[1]-m), pA_=__expf(s2_[2]-m), pB_=__expf(s2_[3]-m);
    float pC_=__expf(s3_[0]-m), pD_=__expf(s3_[1]-m), pE_=__expf(s3_[2]-m), pF_=__expf(s3_[3]-m);
    l += ((((p0_+p1_)+(p2_+p3_)) + ((p4_+p5_)+(p6_+p7_))) +
          (((p8_+p9_)+(pA_+pB_)) + ((pC_+pD_)+(pE_+pF_))));

    uint4 uA_ = { pk2c(p0_,p1_), pk2c(p2_,p3_), pk2c(p4_,p5_), pk2c(p6_,p7_) };
    uint4 uB_ = { pk2c(p8_,p9_), pk2c(pA_,pB_), pk2c(pC_,pD_), pk2c(pE_,pF_) };
    short8v pbA_ = __builtin_bit_cast(short8v, uA_);
    short8v pbB_ = __builtin_bit_cast(short8v, uB_);

    short4 Wa0 = *(const short4*)&Vs[buf][lo][4 * g];
    short4 Wa1 = *(const short4*)&Vs[buf][lo][16 + 4 * g];
    short4 Wa2 = *(const short4*)&Vs[buf][lo][32 + 4 * g];
    short4 Wa3 = *(const short4*)&Vs[buf][lo][48 + 4 * g];
    short4 Xa0 = *(const short4*)&Vs[buf][16 + lo][4 * g];
    short4 Xa1 = *(const short4*)&Vs[buf][16 + lo][16 + 4 * g];
    short4 Xa2 = *(const short4*)&Vs[buf][16 + lo][32 + 4 * g];
    short4 Xa3 = *(const short4*)&Vs[buf][16 + lo][48 + 4 * g];
    short8v va0_ = {Wa0.x,Wa0.y,Wa0.z,Wa0.w, Wa1.x,Wa1.y,Wa1.z,Wa1.w};
    short8v va1_ = {Wa2.x,Wa2.y,Wa2.z,Wa2.w, Wa3.x,Wa3.y,Wa3.z,Wa3.w};
    short8v vb0_ = {Xa0.x,Xa0.y,Xa0.z,Xa0.w, Xa1.x,Xa1.y,Xa1.z,Xa1.w};
    short8v vb1_ = {Xa2.x,Xa2.y,Xa2.z,Xa2.w, Xa3.x,Xa3.y,Xa3.z,Xa3.w};
    acc0 = MFMA16(va0_, pbA_, acc0);
    acc0 = MFMA16(va1_, pbB_, acc0);
    acc1 = MFMA16(vb0_, pbA_, acc1);
    acc1 = MFMA16(vb1_, pbB_, acc1);

    if (more) {
      if (isK) *(short8v*)&Ks[buf ^ 1][krow][kq] = rg;
      else     *(short8v*)&Vs[buf ^ 1][vrow][vo] = rg;
    }
    __syncthreads();
    buf ^= 1;
  }

  l += __shfl_xor(l, 16, 64);
  l += __shfl_xor(l, 32, 64);

  int q = qb + lo;
  float* pr = po + ((size_t)s * NN + q) * DIM + h * 32 + 4 * g;
  *(f32x4*)pr = acc0;
  *(f32x4*)(pr + 16) = acc1;
  if (g == 0) {
    float2* mlp = (float2*)(ml + (((size_t)s * NN + q) * NHEAD + h) * 2);
    *mlp = float2{m, l};
  }
}

// ---------------- merge v2: wave per q-row, float4 po reads ----------------
__global__ __launch_bounds__(256) void attn_merge(const float* __restrict__ po,
                                                  const float* __restrict__ ml,
                                                  unsigned short* __restrict__ attb, int S) {
  int w = threadIdx.x >> 6, lane = threadIdx.x & 63;
  int q = blockIdx.x * 4 + w;
  int c = lane * 4;
  int h = lane >> 3;
  float M = -1e30f;
  for (int s = 0; s < S; s++)
    M = fmaxf(M, ml[(((size_t)s * NN + q) * NHEAD + h) * 2]);
  float L = 0.f;
  float4 O = {0.f, 0.f, 0.f, 0.f};
  for (int s = 0; s < S; s++) {
    const float2 mlv = *(const float2*)(ml + (((size_t)s * NN + q) * NHEAD + h) * 2);
    float e = __expf(mlv.x - M);
    L += e * mlv.y;
    float4 p = *(const float4*)(po + ((size_t)s * NN + q) * DIM + c);
    O.x += e * p.x; O.y += e * p.y; O.z += e * p.z; O.w += e * p.w;
  }
  float inv = 1.f / L;
  ushort4 o;
  o.x = f2bf(O.x * inv); o.y = f2bf(O.y * inv);
  o.z = f2bf(O.z * inv); o.w = f2bf(O.w * inv);
  *(ushort4*)(attb + (size_t)q * DIM + c) = o;
}

// ---------------- merged prep: weight conv + padded input conv + counts zeroing -----------
#define WO0 0
#define WO1 131072
#define WO2 262144
#define WO3 655360
#define WO4 786432
#define WO5 1048576
#define WO6 1310720
#define WTOT 1343488
#define WBLK 1312
#define XPBLK 1536
#define WPBLK 96
#define ZBLK 16
__global__ __launch_bounds__(256) void prep_convert(
    const float* __restrict__ s0, const float* __restrict__ s1,
    const float* __restrict__ s2, const float* __restrict__ s3,
    const float* __restrict__ s4, const float* __restrict__ s5,
    const float* __restrict__ s6, unsigned short* __restrict__ dst,
    const float* __restrict__ x_in, unsigned short* __restrict__ xinb,
    const float* __restrict__ in_w, unsigned short* __restrict__ inwb,
    int* __restrict__ counts) {
  int bid = blockIdx.x;
  if (bid < WBLK) {
    int i4 = (bid * 256 + threadIdx.x) * 4;
    if (i4 >= WTOT) return;
    const float* src; int loc;
    if      (i4 < WO1) { src = s0; loc = i4 - WO0; }
    else if (i4 < WO2) { src = s1; loc = i4 - WO1; }
    else if (i4 < WO3) { src = s2; loc = i4 - WO2; }
    else if (i4 < WO4) { src = s3; loc = i4 - WO3; }
    else if (i4 < WO5) { src = s4; loc = i4 - WO4; }
    else if (i4 < WO6) { src = s5; loc = i4 - WO5; }
    else               { src = s6; loc = i4 - WO6; }
    float4 v = *(const float4*)(src + loc);
    ushort4 o;
    o.x = f2bf(v.x); o.y = f2bf(v.y); o.z = f2bf(v.z); o.w = f2bf(v.w);
    *(ushort4*)(dst + i4) = o;
  } else if (bid < WBLK + XPBLK) {
    int idx = (bid - WBLK) * 256 + threadIdx.x;
    int row = idx / 96, col = idx - row * 96;
    xinb[idx] = (col < 72) ? f2bf(x_in[row * 72 + col]) : (unsigned short)0;
  } else if (bid < WBLK + XPBLK + WPBLK) {
    int idx = (bid - WBLK - XPBLK) * 256 + threadIdx.x;
    int row = idx / 96, col = idx - row * 96;
    inwb[idx] = (col < 72) ? f2bf(in_w[row * 72 + col]) : (unsigned short)0;
  } else {
    int idx = (bid - WBLK - XPBLK - WPBLK) * 256 + threadIdx.x;
    if (idx < NN) counts[idx] = 0;
  }
}

// ---------------- tiny head ----------------
__global__ void head2_kernel(const float* __restrict__ e, const float* __restrict__ w,
                             const float* __restrict__ b, float* __restrict__ out) {
  int idx = blockIdx.x * 256 + threadIdx.x;
  if (idx >= NN * 5) return;
  int rowi = idx / 5, col = idx % 5;
  float s = b[col];
  const float* ep = e + (size_t)rowi * 128;
  const float* wp = w + (size_t)col * 128;
  #pragma unroll 16
  for (int k = 0; k < 128; k++) s += ep[k] * wp[k];
  out[idx] = s;
}

extern "C" void kernel_launch(void* const* d_in, const int* in_sizes, int n_in,
                              void* d_out, int out_size, void* d_ws, size_t ws_size,
                              hipStream_t stream) {
  const float* x_in   = (const float*)d_in[0];
  const int*   ei     = (const int*)  d_in[1];
  const float* in_w   = (const float*)d_in[2];
  const float* in_b   = (const float*)d_in[3];
  const float* head_w1= (const float*)d_in[4];
  const float* head_b1= (const float*)d_in[5];
  const float* head_w2= (const float*)d_in[6];
  const float* head_b2= (const float*)d_in[7];
  const float* mlp_w1 = (const float*)d_in[8];
  const float* mlp_b1 = (const float*)d_in[9];
  const float* mlp_w2 = (const float*)d_in[10];
  const float* mlp_b2 = (const float*)d_in[11];
  const float* gin_eps= (const float*)d_in[12];
  const float* ln1_g  = (const float*)d_in[13];
  const float* ln1_b  = (const float*)d_in[14];
  const float* attn_in_w = (const float*)d_in[15];
  const float* attn_in_b = (const float*)d_in[16];
  const float* attn_out_w= (const float*)d_in[17];
  const float* attn_out_b= (const float*)d_in[18];
  const float* ln2_g  = (const float*)d_in[19];
  const float* ln2_b  = (const float*)d_in[20];
  const float* ffn_w1 = (const float*)d_in[21];
  const float* ffn_b1 = (const float*)d_in[22];
  const float* ffn_w2 = (const float*)d_in[23];
  const float* ffn_b2 = (const float*)d_in[24];
  const float* ln3_g  = (const float*)d_in[25];
  const float* ln3_b  = (const float*)d_in[26];

  float* ws = (float*)d_ws;
  float* x    = ws;
  float* t2   = x  + (size_t)NN * DIM;     // [2][NN][DIM] f32 (split-K partials)
  float* he   = t2 + (size_t)2 * NN * DIM;
  unsigned short* xb   = (unsigned short*)(he + (size_t)NN * 128);
  unsigned short* tbb  = xb   + (size_t)NN * DIM;
  unsigned short* aggb = tbb  + (size_t)NN * 768;
  unsigned short* attb = aggb + (size_t)NN * DIM;
  unsigned short* VT   = attb + (size_t)NN * DIM;
  unsigned short* xinb = VT   + (size_t)NN * DIM;
  unsigned short* inwb = xinb + (size_t)NN * 96;
  unsigned short* warena = inwb + 256 * 96;
  int* counts = (int*)(warena + WTOT);
  int* offs   = counts + NN;
  int* cursor = offs + NN + 1;
  int* esrc   = cursor + NN;
  float* po   = (float*)(esrc + NE);
  size_t used_f = (size_t)(po - ws);
  int S = 1;
  for (int cand = 4; cand >= 2; cand >>= 1) {
    size_t need = (used_f + (size_t)cand * NN * DIM + (size_t)cand * NN * NHEAD * 2) * 4;
    if (ws_size >= need) { S = cand; break; }
  }
  float* ml = po + (size_t)S * NN * DIM;
  int kspan = NN / S;
  // split-K only if workspace accommodates the second t2 buffer + attention scratch
  bool skq = ws_size >= (used_f + (size_t)S * NN * DIM + (size_t)S * NN * NHEAD * 2) * 4;

  const unsigned short* w_mlp1 = warena + WO0;
  const unsigned short* w_mlp2 = warena + WO1;
  const unsigned short* w_qkv  = warena + WO2;
  const unsigned short* w_aout = warena + WO3;
  const unsigned short* w_ffn1 = warena + WO4;
  const unsigned short* w_ffn2 = warena + WO5;
  const unsigned short* w_h1   = warena + WO6;

  // merged conversions + counts zeroing (stream-ordered before count_edges)
  prep_convert<<<WBLK + XPBLK + WPBLK + ZBLK, 256, 0, stream>>>(
      mlp_w1, mlp_w2, attn_in_w, attn_out_w, ffn_w1, ffn_w2, head_w1, warena,
      x_in, xinb, in_w, inwb, counts);

  // CSR build
  count_edges<<<NE / 256, 256, 0, stream>>>(ei, counts);
  scan_offsets<<<1, 1024, 0, stream>>>(counts, offs, cursor);
  scatter_edges<<<NE / 256, 256, 0, stream>>>(ei, cursor, esrc);

  // input projection (K=96 -> BK=32)
  gemm_mfma<1,1,1,0,32><<<dim3(DIM/32, NN/64), 256, 0, stream>>>(xinb, inwb, in_b, x, xb,
                                                                 NN, DIM, 96);

  for (int l = 0; l < 2; l++) {
    // GIN
    gin_agg<<<NN / 4, 256, 0, stream>>>(offs, esrc, xb, gin_eps, l, aggb);
    gemm_mfma<1,0,1,0,64><<<dim3(8, 64), 256, 0, stream>>>(aggb, w_mlp1 + (size_t)l*65536,
                                                           mlp_b1 + l*DIM, nullptr, tbb,
                                                           NN, DIM, DIM);
    if (skq) {
      gemm_mfma<0,1,0,0,64,0,2><<<dim3(8, 64, 2), 256, 0, stream>>>(
          tbb, w_mlp2 + (size_t)l*65536, mlp_b2 + l*DIM, t2, nullptr, NN, DIM, DIM);
      ln_act_add<1,2><<<NN / 4, 256, 0, stream>>>(t2, ln1_g + l*DIM, ln1_b + l*DIM, x, xb);
    } else {
      gemm_mfma<0,1,0,0,64><<<dim3(8, 64), 256, 0, stream>>>(
          tbb, w_mlp2 + (size_t)l*65536, mlp_b2 + l*DIM, t2, nullptr, NN, DIM, DIM);
      ln_act_add<1,1><<<NN / 4, 256, 0, stream>>>(t2, ln1_g + l*DIM, ln1_b + l*DIM, x, xb);
    }

    // attention: qkv GEMM writes Q,K to tbb and V transposed to VT (fused)
    gemm_mfma<0,0,1,1,64,1><<<dim3(24, 64), 256, 0, stream>>>(xb, w_qkv + (size_t)l*196608,
                                                              attn_in_b + l*768, nullptr, tbb,
                                                              NN, 768, DIM, VT);
    attn_mfma_split<<<dim3(32, NHEAD, S), 512, 0, stream>>>(tbb, VT, po, ml, kspan);
    attn_merge<<<NN / 4, 256, 0, stream>>>(po, ml, attb, S);
    if (skq) {
      gemm_mfma<0,1,0,0,64,0,2><<<dim3(8, 64, 2), 256, 0, stream>>>(
          attb, w_aout + (size_t)l*65536, attn_out_b + l*DIM, t2, nullptr, NN, DIM, DIM);
      ln_act_add<0,2><<<NN / 4, 256, 0, stream>>>(t2, ln2_g + l*DIM, ln2_b + l*DIM, x, xb);
    } else {
      gemm_mfma<0,1,0,0,64><<<dim3(8, 64), 256, 0, stream>>>(
          attb, w_aout + (size_t)l*65536, attn_out_b + l*DIM, t2, nullptr, NN, DIM, DIM);
      ln_act_add<0,1><<<NN / 4, 256, 0, stream>>>(t2, ln2_g + l*DIM, ln2_b + l*DIM, x, xb);
    }

    // FFN
    gemm_mfma<2,0,1,0,64><<<dim3(16, 64), 256, 0, stream>>>(xb, w_ffn1 + (size_t)l*131072,
                                                            ffn_b1 + l*512, nullptr, tbb,
                                                            NN, 512, DIM);
    if (skq) {
      gemm_mfma<0,1,0,0,64,0,2><<<dim3(8, 64, 2), 256, 0, stream>>>(
          tbb, w_ffn2 + (size_t)l*131072, ffn_b2 + l*DIM, t2, nullptr, NN, DIM, 512);
      ln_act_add<0,2><<<NN / 4, 256, 0, stream>>>(t2, ln3_g + l*DIM, ln3_b + l*DIM, x, xb);
    } else {
      gemm_mfma<0,1,0,0,64><<<dim3(8, 64), 256, 0, stream>>>(
          tbb, w_ffn2 + (size_t)l*131072, ffn_b2 + l*DIM, t2, nullptr, NN, DIM, 512);
      ln_act_add<0,1><<<NN / 4, 256, 0, stream>>>(t2, ln3_g + l*DIM, ln3_b + l*DIM, x, xb);
    }
  }

  // head
  gemm_mfma<1,1,0,0,64><<<dim3(4, 64), 256, 0, stream>>>(xb, w_h1, head_b1, he, nullptr,
                                                         NN, 128, DIM);
  head2_kernel<<<(NN * 5 + 255) / 256, 256, 0, stream>>>(he, head_w2, head_b2, (float*)d_out);
}

// Round 18
// 297.129 us; speedup vs baseline: 1.0182x; 1.0182x over previous
//
#include <hip/hip_runtime.h>
#include <hip/hip_bf16.h>
#include <math.h>

#define NN 4096
#define NE 131072
#define DIM 256
#define NHEAD 8
#define HD 32

typedef __attribute__((ext_vector_type(8))) short short8v;
typedef __attribute__((ext_vector_type(4))) float f32x4;
#define MFMA16(a, b, c) __builtin_amdgcn_mfma_f32_16x16x32_bf16(a, b, c, 0, 0, 0)

__device__ __forceinline__ float elu_f(float v){ return v > 0.f ? v : expm1f(v); }
__device__ __forceinline__ float gelu_f(float v){
  const float c = 0.7978845608028654f;
  float t = tanhf(c * (v + 0.044715f * v * v * v));
  return 0.5f * v * (1.f + t);
}
__device__ __forceinline__ unsigned short f2bf(float f) {
  unsigned int u = __builtin_bit_cast(unsigned int, f);
  u += 0x7FFFu + ((u >> 16) & 1u);
  return (unsigned short)(u >> 16);
}
__device__ __forceinline__ float bf2f(unsigned short u) {
  return __builtin_bit_cast(float, (unsigned int)u << 16);
}
__device__ __forceinline__ unsigned int pk2c(float a, float b) {
  __hip_bfloat162 h = __float22bfloat162_rn(float2{a, b});
  unsigned int r;
  __builtin_memcpy(&r, &h, 4);
  return r;
}

// ---------------- CSR build ----------------
__global__ void count_edges(const int* __restrict__ ei, int* __restrict__ counts) {
  int e = blockIdx.x * 256 + threadIdx.x;
  if (e < NE) atomicAdd(&counts[ei[NE + e]], 1);
}

__global__ __launch_bounds__(1024) void scan_offsets(const int* __restrict__ counts,
                                                     int* __restrict__ offs,
                                                     int* __restrict__ cursor) {
  __shared__ int tmp[1024];
  int t = threadIdx.x;
  int base = t * 4;
  int c0 = counts[base], c1 = counts[base+1], c2 = counts[base+2], c3 = counts[base+3];
  int tsum = c0 + c1 + c2 + c3;
  tmp[t] = tsum;
  __syncthreads();
  for (int d = 1; d < 1024; d <<= 1) {
    int v = (t >= d) ? tmp[t - d] : 0;
    __syncthreads();
    tmp[t] += v;
    __syncthreads();
  }
  int excl = tmp[t] - tsum;
  offs[base]   = excl;           cursor[base]   = excl;
  offs[base+1] = excl + c0;      cursor[base+1] = excl + c0;
  offs[base+2] = excl + c0 + c1; cursor[base+2] = excl + c0 + c1;
  offs[base+3] = excl + c0 + c1 + c2; cursor[base+3] = excl + c0 + c1 + c2;
  if (t == 1023) offs[NN] = tmp[1023];
}

__global__ void scatter_edges(const int* __restrict__ ei, int* __restrict__ cursor,
                              int* __restrict__ esrc) {
  int e = blockIdx.x * 256 + threadIdx.x;
  if (e < NE) {
    int d = ei[NE + e];
    int pos = atomicAdd(&cursor[d], 1);
    esrc[pos] = ei[e];
  }
}

// ---------------- GIN aggregate v2: wave per node, ushort4 (8B/lane) gather ----------------
__global__ __launch_bounds__(256) void gin_agg(const int* __restrict__ offs,
                                               const int* __restrict__ esrc,
                                               const unsigned short* __restrict__ xb,
                                               const float* __restrict__ eps_p, int l,
                                               unsigned short* __restrict__ aggb) {
  int w = threadIdx.x >> 6, lane = threadIdx.x & 63;
  int n = blockIdx.x * 4 + w;
  int c = lane * 4;
  int e0 = offs[n], e1 = offs[n + 1];
  float a0 = 0.f, a1 = 0.f, a2 = 0.f, a3 = 0.f;
  for (int e = e0; e < e1; e++) {
    ushort4 v = *(const ushort4*)(xb + (size_t)esrc[e] * DIM + c);
    a0 += bf2f(v.x); a1 += bf2f(v.y); a2 += bf2f(v.z); a3 += bf2f(v.w);
  }
  float eps = 1.f + eps_p[l];
  ushort4 xv = *(const ushort4*)(xb + (size_t)n * DIM + c);
  ushort4 o;
  o.x = f2bf(eps * bf2f(xv.x) + a0);
  o.y = f2bf(eps * bf2f(xv.y) + a1);
  o.z = f2bf(eps * bf2f(xv.z) + a2);
  o.w = f2bf(eps * bf2f(xv.w) + a3);
  *(ushort4*)(aggb + (size_t)n * DIM + c) = o;
}

// ---------------- bf16 MFMA GEMM v3: 64x32 tile + register double-buffer staging ----------
template<int ACT, int WF32, int WBF16, int QSCALE, int BK, int WVT = 0>
__global__ __launch_bounds__(256) void gemm_mfma(
    const unsigned short* __restrict__ A, const unsigned short* __restrict__ W,
    const float* __restrict__ bias, float* __restrict__ Cf,
    unsigned short* __restrict__ Cb, int M, int N, int K,
    unsigned short* __restrict__ VTout = nullptr)
{
  __shared__ __align__(16) unsigned short As[2][64][BK + 8];
  __shared__ __align__(16) unsigned short Ws[2][32][BK + 8];
  constexpr int CPR = BK / 8;
  constexpr int ACH = 64 * CPR;
  constexpr int WCH = 32 * CPR;
  constexpr int NA = (ACH + 255) / 256;
  constexpr int NW = (WCH + 255) / 256;
  int t = threadIdx.x;
  int w = t >> 6, lane = t & 63, lo = lane & 15, g = lane >> 4;
  int wm = w & 1, wn = w >> 1;
  int bn = blockIdx.x * 32, bm = blockIdx.y * 64;

  f32x4 acc0 = {0.f, 0.f, 0.f, 0.f};
  f32x4 acc1 = {0.f, 0.f, 0.f, 0.f};
  short8v pa[NA], pw[NW];

  auto LOADG = [&](int k0) {
    #pragma unroll
    for (int i = 0; i < NA; i++) {
      int cc = i * 256 + t;
      int row = cc / CPR, off = (cc % CPR) * 8;
      pa[i] = *(const short8v*)(A + (size_t)(bm + row) * K + k0 + off);
    }
    #pragma unroll
    for (int i = 0; i < NW; i++) {
      int cc = i * 256 + t;
      if (cc < WCH) {
        int row = cc / CPR, off = (cc % CPR) * 8;
        pw[i] = *(const short8v*)(W + (size_t)(bn + row) * K + k0 + off);
      }
    }
  };
  auto STORE = [&](int b) {
    #pragma unroll
    for (int i = 0; i < NA; i++) {
      int cc = i * 256 + t;
      int row = cc / CPR, off = (cc % CPR) * 8;
      *(short8v*)&As[b][row][off] = pa[i];
    }
    #pragma unroll
    for (int i = 0; i < NW; i++) {
      int cc = i * 256 + t;
      if (cc < WCH) {
        int row = cc / CPR, off = (cc % CPR) * 8;
        *(short8v*)&Ws[b][row][off] = pw[i];
      }
    }
  };

  LOADG(0);
  STORE(0);
  __syncthreads();

  int buf = 0;
  for (int k0 = 0; k0 < K; k0 += BK) {
    bool more = (k0 + BK < K);
    if (more) LOADG(k0 + BK);
    #pragma unroll
    for (int ks = 0; ks < BK; ks += 32) {
      short8v a0 = *(const short8v*)&As[buf][wm * 32 + lo][ks + 8 * g];
      short8v a1 = *(const short8v*)&As[buf][wm * 32 + 16 + lo][ks + 8 * g];
      short8v b0 = *(const short8v*)&Ws[buf][wn * 16 + lo][ks + 8 * g];
      acc0 = MFMA16(a0, b0, acc0);
      acc1 = MFMA16(a1, b0, acc1);
    }
    if (more) STORE(buf ^ 1);
    __syncthreads();
    buf ^= 1;
  }

  #pragma unroll
  for (int mi = 0; mi < 2; mi++) {
    f32x4 av = (mi == 0) ? acc0 : acc1;
    int col = bn + wn * 16 + lo;
    int rbase = bm + wm * 32 + mi * 16 + 4 * g;
    if (WVT && col >= 512) {
      ushort4 o;
      float v0 = av[0] + bias[col], v1 = av[1] + bias[col];
      float v2 = av[2] + bias[col], v3 = av[3] + bias[col];
      o.x = f2bf(v0); o.y = f2bf(v1); o.z = f2bf(v2); o.w = f2bf(v3);
      *(ushort4*)(VTout + (size_t)(col - 512) * 4096 + rbase) = o;
    } else {
      #pragma unroll
      for (int r = 0; r < 4; r++) {
        int row = rbase + r;
        float v = av[r] + bias[col];
        if (ACT == 1) v = elu_f(v);
        if (ACT == 2) v = gelu_f(v);
        if (QSCALE) { if (col < 256) v *= 0.17677669529663687f; }
        if (WF32) Cf[(size_t)row * N + col] = v;
        if (WBF16) Cb[(size_t)row * N + col] = f2bf(v);
      }
    }
  }
}

// ---------------- LayerNorm v2: wave per row, float4 I/O, in-wave-only reduce --------------
template<int ACT>
__global__ __launch_bounds__(256) void ln_act_add(const float* __restrict__ in,
                                                  const float* __restrict__ g,
                                                  const float* __restrict__ b,
                                                  float* __restrict__ x,
                                                  unsigned short* __restrict__ xb) {
  int w = threadIdx.x >> 6, lane = threadIdx.x & 63;
  int row = blockIdx.x * 4 + w;
  int c = lane * 4;
  float4 v = *(const float4*)(in + (size_t)row * DIM + c);
  float s  = (v.x + v.y) + (v.z + v.w);
  float s2 = (v.x * v.x + v.y * v.y) + (v.z * v.z + v.w * v.w);
  #pragma unroll
  for (int off = 32; off >= 1; off >>= 1) {
    s  += __shfl_xor(s,  off, 64);
    s2 += __shfl_xor(s2, off, 64);
  }
  float mean = s * (1.f / DIM);
  float var = s2 * (1.f / DIM) - mean * mean;
  float r = rsqrtf(var + 1e-5f);
  float4 gg = *(const float4*)(g + c);
  float4 bb = *(const float4*)(b + c);
  float4 o;
  o.x = (v.x - mean) * r * gg.x + bb.x;
  o.y = (v.y - mean) * r * gg.y + bb.y;
  o.z = (v.z - mean) * r * gg.z + bb.z;
  o.w = (v.w - mean) * r * gg.w + bb.w;
  if (ACT == 1) { o.x = elu_f(o.x); o.y = elu_f(o.y); o.z = elu_f(o.z); o.w = elu_f(o.w); }
  float4 xv = *(const float4*)(x + (size_t)row * DIM + c);
  xv.x += o.x; xv.y += o.y; xv.z += o.z; xv.w += o.w;
  *(float4*)(x + (size_t)row * DIM + c) = xv;
  ushort4 xo;
  xo.x = f2bf(xv.x); xo.y = f2bf(xv.y); xo.z = f2bf(xv.z); xo.w = f2bf(xv.w);
  *(ushort4*)(xb + (size_t)row * DIM + c) = xo;
}

// ---------------- MFMA flash attention v7b: 8-wave QB=128, LDS K/V, in-reg SM, bf16 po ----
__global__ __launch_bounds__(512) void attn_mfma_split(
    const unsigned short* __restrict__ qkvb, const unsigned short* __restrict__ VT,
    unsigned short* __restrict__ po, float* __restrict__ ml, int kspan) {
  __shared__ __align__(16) unsigned short Ks[2][64][40];
  __shared__ __align__(16) unsigned short Vs[2][32][72];
  int tid = threadIdx.x;
  int w = tid >> 6, lane = tid & 63;
  int lo = lane & 15, g = lane >> 4;
  int h = blockIdx.y;
  int s = blockIdx.z;
  int qb = blockIdx.x * 128 + w * 16;
  int k_lo = s * kspan, k_hi = k_lo + kspan;

  bool isK = tid < 256;
  int krow = tid >> 2, kq = (tid & 3) * 8;
  int vtid = tid & 255;
  int vrow = vtid >> 3, vo = (vtid & 7) * 8;
  const unsigned short* Kg = qkvb + 256 + h * 32;
  const unsigned short* Vg = VT + ((size_t)(h * 32 + vrow)) * 4096;

  short8v qf = *(const short8v*)(qkvb + (size_t)(qb + lo) * 768 + h * 32 + 8 * g);

  f32x4 acc0 = {0.f, 0.f, 0.f, 0.f};
  f32x4 acc1 = {0.f, 0.f, 0.f, 0.f};
  float m = -1e30f, l = 0.f;
  const f32x4 zf = {0.f, 0.f, 0.f, 0.f};

  {
    if (isK) {
      short8v rk0 = *(const short8v*)(Kg + (size_t)(k_lo + krow) * 768 + kq);
      *(short8v*)&Ks[0][krow][kq] = rk0;
    } else {
      short8v rv0 = *(const short8v*)(Vg + k_lo + vo);
      *(short8v*)&Vs[0][vrow][vo] = rv0;
    }
  }
  __syncthreads();

  int buf = 0;
  for (int kb = k_lo; kb < k_hi; kb += 64) {
    short8v rg;
    bool more = (kb + 64 < k_hi);
    if (more) {
      if (isK) rg = *(const short8v*)(Kg + (size_t)(kb + 64 + krow) * 768 + kq);
      else     rg = *(const short8v*)(Vg + kb + 64 + vo);
    }

    short8v kA0 = *(const short8v*)&Ks[buf][lo][8 * g];
    short8v kA1 = *(const short8v*)&Ks[buf][16 + lo][8 * g];
    short8v kA2 = *(const short8v*)&Ks[buf][32 + lo][8 * g];
    short8v kA3 = *(const short8v*)&Ks[buf][48 + lo][8 * g];
    f32x4 s0_ = MFMA16(kA0, qf, zf);
    f32x4 s1_ = MFMA16(kA1, qf, zf);
    f32x4 s2_ = MFMA16(kA2, qf, zf);
    f32x4 s3_ = MFMA16(kA3, qf, zf);

    float ta_ = fmaxf(fmaxf(fmaxf(s0_[0],s0_[1]), fmaxf(s0_[2],s0_[3])),
                      fmaxf(fmaxf(s1_[0],s1_[1]), fmaxf(s1_[2],s1_[3])));
    float tb_ = fmaxf(fmaxf(fmaxf(s2_[0],s2_[1]), fmaxf(s2_[2],s2_[3])),
                      fmaxf(fmaxf(s3_[0],s3_[1]), fmaxf(s3_[2],s3_[3])));
    float t_ = fmaxf(ta_, tb_);
    t_ = fmaxf(t_, __shfl_xor(t_, 16, 64));
    t_ = fmaxf(t_, __shfl_xor(t_, 32, 64));
    if (!__all(t_ <= m)) {
      float nm_ = fmaxf(m, t_);
      float f_ = __expf(m - nm_);
      m = nm_; l *= f_;
      acc0[0]*=f_; acc0[1]*=f_; acc0[2]*=f_; acc0[3]*=f_;
      acc1[0]*=f_; acc1[1]*=f_; acc1[2]*=f_; acc1[3]*=f_;
    }
    float p0_=__expf(s0_[0]-m), p1_=__expf(s0_[1]-m), p2_=__expf(s0_[2]-m), p3_=__expf(s0_[3]-m);
    float p4_=__expf(s1_[0]-m), p5_=__expf(s1_[1]-m), p6_=__expf(s1_[2]-m), p7_=__expf(s1_[3]-m);
    float p8_=__expf(s2_[0]-m), p9_=__expf(s2_[1]-m), pA_=__expf(s2_[2]-m), pB_=__expf(s2_[3]-m);
    float pC_=__expf(s3_[0]-m), pD_=__expf(s3_[1]-m), pE_=__expf(s3_[2]-m), pF_=__expf(s3_[3]-m);
    l += ((((p0_+p1_)+(p2_+p3_)) + ((p4_+p5_)+(p6_+p7_))) +
          (((p8_+p9_)+(pA_+pB_)) + ((pC_+pD_)+(pE_+pF_))));

    uint4 uA_ = { pk2c(p0_,p1_), pk2c(p2_,p3_), pk2c(p4_,p5_), pk2c(p6_,p7_) };
    uint4 uB_ = { pk2c(p8_,p9_), pk2c(pA_,pB_), pk2c(pC_,pD_), pk2c(pE_,pF_) };
    short8v pbA_ = __builtin_bit_cast(short8v, uA_);
    short8v pbB_ = __builtin_bit_cast(short8v, uB_);

    short4 Wa0 = *(const short4*)&Vs[buf][lo][4 * g];
    short4 Wa1 = *(const short4*)&Vs[buf][lo][16 + 4 * g];
    short4 Wa2 = *(const short4*)&Vs[buf][lo][32 + 4 * g];
    short4 Wa3 = *(const short4*)&Vs[buf][lo][48 + 4 * g];
    short4 Xa0 = *(const short4*)&Vs[buf][16 + lo][4 * g];
    short4 Xa1 = *(const short4*)&Vs[buf][16 + lo][16 + 4 * g];
    short4 Xa2 = *(const short4*)&Vs[buf][16 + lo][32 + 4 * g];
    short4 Xa3 = *(const short4*)&Vs[buf][16 + lo][48 + 4 * g];
    short8v va0_ = {Wa0.x,Wa0.y,Wa0.z,Wa0.w, Wa1.x,Wa1.y,Wa1.z,Wa1.w};
    short8v va1_ = {Wa2.x,Wa2.y,Wa2.z,Wa2.w, Wa3.x,Wa3.y,Wa3.z,Wa3.w};
    short8v vb0_ = {Xa0.x,Xa0.y,Xa0.z,Xa0.w, Xa1.x,Xa1.y,Xa1.z,Xa1.w};
    short8v vb1_ = {Xa2.x,Xa2.y,Xa2.z,Xa2.w, Xa3.x,Xa3.y,Xa3.z,Xa3.w};
    acc0 = MFMA16(va0_, pbA_, acc0);
    acc0 = MFMA16(va1_, pbB_, acc0);
    acc1 = MFMA16(vb0_, pbA_, acc1);
    acc1 = MFMA16(vb1_, pbB_, acc1);

    if (more) {
      if (isK) *(short8v*)&Ks[buf ^ 1][krow][kq] = rg;
      else     *(short8v*)&Vs[buf ^ 1][vrow][vo] = rg;
    }
    __syncthreads();
    buf ^= 1;
  }

  l += __shfl_xor(l, 16, 64);
  l += __shfl_xor(l, 32, 64);

  int q = qb + lo;
  unsigned short* pr = po + ((size_t)s * NN + q) * DIM + h * 32 + 4 * g;
  uint2 w0 = { pk2c(acc0[0], acc0[1]), pk2c(acc0[2], acc0[3]) };
  uint2 w1 = { pk2c(acc1[0], acc1[1]), pk2c(acc1[2], acc1[3]) };
  *(uint2*)pr = w0;
  *(uint2*)(pr + 16) = w1;
  if (g == 0) {
    float2* mlp = (float2*)(ml + (((size_t)s * NN + q) * NHEAD + h) * 2);
    *mlp = float2{m, l};
  }
}

// ---------------- merge v3: wave per q-row, bf16 po reads (half traffic) ----------------
__global__ __launch_bounds__(256) void attn_merge(const unsigned short* __restrict__ po,
                                                  const float* __restrict__ ml,
                                                  unsigned short* __restrict__ attb, int S) {
  int w = threadIdx.x >> 6, lane = threadIdx.x & 63;
  int q = blockIdx.x * 4 + w;
  int c = lane * 4;
  int h = lane >> 3;
  float M = -1e30f;
  for (int s = 0; s < S; s++)
    M = fmaxf(M, ml[(((size_t)s * NN + q) * NHEAD + h) * 2]);
  float L = 0.f;
  float4 O = {0.f, 0.f, 0.f, 0.f};
  for (int s = 0; s < S; s++) {
    const float2 mlv = *(const float2*)(ml + (((size_t)s * NN + q) * NHEAD + h) * 2);
    float e = __expf(mlv.x - M);
    L += e * mlv.y;
    ushort4 p = *(const ushort4*)(po + ((size_t)s * NN + q) * DIM + c);
    O.x += e * bf2f(p.x); O.y += e * bf2f(p.y);
    O.z += e * bf2f(p.z); O.w += e * bf2f(p.w);
  }
  float inv = 1.f / L;
  ushort4 o;
  o.x = f2bf(O.x * inv); o.y = f2bf(O.y * inv);
  o.z = f2bf(O.z * inv); o.w = f2bf(O.w * inv);
  *(ushort4*)(attb + (size_t)q * DIM + c) = o;
}

// ---------------- merged prep: weight conv + padded input conv + counts zeroing -----------
#define WO0 0
#define WO1 131072
#define WO2 262144
#define WO3 655360
#define WO4 786432
#define WO5 1048576
#define WO6 1310720
#define WTOT 1343488
#define WBLK 1312
#define XPBLK 1536
#define WPBLK 96
#define ZBLK 16
__global__ __launch_bounds__(256) void prep_convert(
    const float* __restrict__ s0, const float* __restrict__ s1,
    const float* __restrict__ s2, const float* __restrict__ s3,
    const float* __restrict__ s4, const float* __restrict__ s5,
    const float* __restrict__ s6, unsigned short* __restrict__ dst,
    const float* __restrict__ x_in, unsigned short* __restrict__ xinb,
    const float* __restrict__ in_w, unsigned short* __restrict__ inwb,
    int* __restrict__ counts) {
  int bid = blockIdx.x;
  if (bid < WBLK) {
    int i4 = (bid * 256 + threadIdx.x) * 4;
    if (i4 >= WTOT) return;
    const float* src; int loc;
    if      (i4 < WO1) { src = s0; loc = i4 - WO0; }
    else if (i4 < WO2) { src = s1; loc = i4 - WO1; }
    else if (i4 < WO3) { src = s2; loc = i4 - WO2; }
    else if (i4 < WO4) { src = s3; loc = i4 - WO3; }
    else if (i4 < WO5) { src = s4; loc = i4 - WO4; }
    else if (i4 < WO6) { src = s5; loc = i4 - WO5; }
    else               { src = s6; loc = i4 - WO6; }
    float4 v = *(const float4*)(src + loc);
    ushort4 o;
    o.x = f2bf(v.x); o.y = f2bf(v.y); o.z = f2bf(v.z); o.w = f2bf(v.w);
    *(ushort4*)(dst + i4) = o;
  } else if (bid < WBLK + XPBLK) {
    int idx = (bid - WBLK) * 256 + threadIdx.x;
    int row = idx / 96, col = idx - row * 96;
    xinb[idx] = (col < 72) ? f2bf(x_in[row * 72 + col]) : (unsigned short)0;
  } else if (bid < WBLK + XPBLK + WPBLK) {
    int idx = (bid - WBLK - XPBLK) * 256 + threadIdx.x;
    int row = idx / 96, col = idx - row * 96;
    inwb[idx] = (col < 72) ? f2bf(in_w[row * 72 + col]) : (unsigned short)0;
  } else {
    int idx = (bid - WBLK - XPBLK - WPBLK) * 256 + threadIdx.x;
    if (idx < NN) counts[idx] = 0;
  }
}

// ---------------- tiny head ----------------
__global__ void head2_kernel(const float* __restrict__ e, const float* __restrict__ w,
                             const float* __restrict__ b, float* __restrict__ out) {
  int idx = blockIdx.x * 256 + threadIdx.x;
  if (idx >= NN * 5) return;
  int rowi = idx / 5, col = idx % 5;
  float s = b[col];
  const float* ep = e + (size_t)rowi * 128;
  const float* wp = w + (size_t)col * 128;
  #pragma unroll 16
  for (int k = 0; k < 128; k++) s += ep[k] * wp[k];
  out[idx] = s;
}

extern "C" void kernel_launch(void* const* d_in, const int* in_sizes, int n_in,
                              void* d_out, int out_size, void* d_ws, size_t ws_size,
                              hipStream_t stream) {
  const float* x_in   = (const float*)d_in[0];
  const int*   ei     = (const int*)  d_in[1];
  const float* in_w   = (const float*)d_in[2];
  const float* in_b   = (const float*)d_in[3];
  const float* head_w1= (const float*)d_in[4];
  const float* head_b1= (const float*)d_in[5];
  const float* head_w2= (const float*)d_in[6];
  const float* head_b2= (const float*)d_in[7];
  const float* mlp_w1 = (const float*)d_in[8];
  const float* mlp_b1 = (const float*)d_in[9];
  const float* mlp_w2 = (const float*)d_in[10];
  const float* mlp_b2 = (const float*)d_in[11];
  const float* gin_eps= (const float*)d_in[12];
  const float* ln1_g  = (const float*)d_in[13];
  const float* ln1_b  = (const float*)d_in[14];
  const float* attn_in_w = (const float*)d_in[15];
  const float* attn_in_b = (const float*)d_in[16];
  const float* attn_out_w= (const float*)d_in[17];
  const float* attn_out_b= (const float*)d_in[18];
  const float* ln2_g  = (const float*)d_in[19];
  const float* ln2_b  = (const float*)d_in[20];
  const float* ffn_w1 = (const float*)d_in[21];
  const float* ffn_b1 = (const float*)d_in[22];
  const float* ffn_w2 = (const float*)d_in[23];
  const float* ffn_b2 = (const float*)d_in[24];
  const float* ln3_g  = (const float*)d_in[25];
  const float* ln3_b  = (const float*)d_in[26];

  float* ws = (float*)d_ws;
  float* x    = ws;
  float* t2   = x  + (size_t)NN * DIM;
  float* he   = t2 + (size_t)NN * DIM;
  unsigned short* xb   = (unsigned short*)(he + (size_t)NN * 128);
  unsigned short* tbb  = xb   + (size_t)NN * DIM;
  unsigned short* aggb = tbb  + (size_t)NN * 768;
  unsigned short* attb = aggb + (size_t)NN * DIM;
  unsigned short* VT   = attb + (size_t)NN * DIM;
  unsigned short* xinb = VT   + (size_t)NN * DIM;
  unsigned short* inwb = xinb + (size_t)NN * 96;
  unsigned short* warena = inwb + 256 * 96;
  int* counts = (int*)(warena + WTOT);
  int* offs   = counts + NN;
  int* cursor = offs + NN + 1;
  int* esrc   = cursor + NN;
  unsigned short* po = (unsigned short*)(esrc + NE);   // [S][NN][DIM] bf16
  size_t used_b = (size_t)((char*)po - (char*)ws);
  int S = 1;
  for (int cand = 4; cand >= 2; cand >>= 1) {
    size_t need = used_b + (size_t)cand * NN * DIM * 2 + (size_t)cand * NN * NHEAD * 8;
    if (ws_size >= need) { S = cand; break; }
  }
  float* ml = (float*)(po + (size_t)S * NN * DIM);
  int kspan = NN / S;

  const unsigned short* w_mlp1 = warena + WO0;
  const unsigned short* w_mlp2 = warena + WO1;
  const unsigned short* w_qkv  = warena + WO2;
  const unsigned short* w_aout = warena + WO3;
  const unsigned short* w_ffn1 = warena + WO4;
  const unsigned short* w_ffn2 = warena + WO5;
  const unsigned short* w_h1   = warena + WO6;

  // merged conversions + counts zeroing (stream-ordered before count_edges)
  prep_convert<<<WBLK + XPBLK + WPBLK + ZBLK, 256, 0, stream>>>(
      mlp_w1, mlp_w2, attn_in_w, attn_out_w, ffn_w1, ffn_w2, head_w1, warena,
      x_in, xinb, in_w, inwb, counts);

  // CSR build
  count_edges<<<NE / 256, 256, 0, stream>>>(ei, counts);
  scan_offsets<<<1, 1024, 0, stream>>>(counts, offs, cursor);
  scatter_edges<<<NE / 256, 256, 0, stream>>>(ei, cursor, esrc);

  // input projection (K=96 -> BK=32)
  gemm_mfma<1,1,1,0,32><<<dim3(DIM/32, NN/64), 256, 0, stream>>>(xinb, inwb, in_b, x, xb,
                                                                 NN, DIM, 96);

  for (int l = 0; l < 2; l++) {
    // GIN
    gin_agg<<<NN / 4, 256, 0, stream>>>(offs, esrc, xb, gin_eps, l, aggb);
    gemm_mfma<1,0,1,0,64><<<dim3(8, 64), 256, 0, stream>>>(aggb, w_mlp1 + (size_t)l*65536,
                                                           mlp_b1 + l*DIM, nullptr, tbb,
                                                           NN, DIM, DIM);
    gemm_mfma<0,1,0,0,64><<<dim3(8, 64), 256, 0, stream>>>(tbb, w_mlp2 + (size_t)l*65536,
                                                           mlp_b2 + l*DIM, t2, nullptr,
                                                           NN, DIM, DIM);
    ln_act_add<1><<<NN / 4, 256, 0, stream>>>(t2, ln1_g + l*DIM, ln1_b + l*DIM, x, xb);

    // attention: qkv GEMM writes Q,K to tbb and V transposed to VT (fused)
    gemm_mfma<0,0,1,1,64,1><<<dim3(24, 64), 256, 0, stream>>>(xb, w_qkv + (size_t)l*196608,
                                                              attn_in_b + l*768, nullptr, tbb,
                                                              NN, 768, DIM, VT);
    attn_mfma_split<<<dim3(32, NHEAD, S), 512, 0, stream>>>(tbb, VT, po, ml, kspan);
    attn_merge<<<NN / 4, 256, 0, stream>>>(po, ml, attb, S);
    gemm_mfma<0,1,0,0,64><<<dim3(8, 64), 256, 0, stream>>>(attb, w_aout + (size_t)l*65536,
                                                           attn_out_b + l*DIM, t2, nullptr,
                                                           NN, DIM, DIM);
    ln_act_add<0><<<NN / 4, 256, 0, stream>>>(t2, ln2_g + l*DIM, ln2_b + l*DIM, x, xb);

    // FFN
    gemm_mfma<2,0,1,0,64><<<dim3(16, 64), 256, 0, stream>>>(xb, w_ffn1 + (size_t)l*131072,
                                                            ffn_b1 + l*512, nullptr, tbb,
                                                            NN, 512, DIM);
    gemm_mfma<0,1,0,0,64><<<dim3(8, 64), 256, 0, stream>>>(tbb, w_ffn2 + (size_t)l*131072,
                                                           ffn_b2 + l*DIM, t2, nullptr,
                                                           NN, DIM, 512);
    ln_act_add<0><<<NN / 4, 256, 0, stream>>>(t2, ln3_g + l*DIM, ln3_b + l*DIM, x, xb);
  }

  // head
  gemm_mfma<1,1,0,0,64><<<dim3(4, 64), 256, 0, stream>>>(xb, w_h1, head_b1, he, nullptr,
                                                         NN, 128, DIM);
  head2_kernel<<<(NN * 5 + 255) / 256, 256, 0, stream>>>(he, head_w2, head_b2, (float*)d_out);
}